// Round 14
// baseline (303.853 us; speedup 1.0000x reference)
//
#include <hip/hip_runtime.h>

#define H_DIM 1024
#define T_DIM 4096
#define B_DIM 4
#define M_DIM (B_DIM * T_DIM)   // 16384
#define SCAN_C 64
#define SCAN_W 48

typedef __attribute__((ext_vector_type(8))) short short8;
typedef __attribute__((ext_vector_type(4))) float f32x4;
typedef _Float16 half8 __attribute__((ext_vector_type(8)));

__device__ __forceinline__ unsigned short f2h(float f) {
  _Float16 h = (_Float16)f;
  return __builtin_bit_cast(unsigned short, h);
}
__device__ __forceinline__ float h2f(unsigned short u) {
  return (float)__builtin_bit_cast(_Float16, u);
}

// ------- fused prep: xs split (blocks 0..16383) + weight prep (blocks 16384..20479) -------
__global__ void prep_kernel(const float* __restrict__ x,
                            const float* __restrict__ Wrec, const float* __restrict__ Wkey,
                            const float* __restrict__ Wval, const float* __restrict__ Wout,
                            const float* __restrict__ tmk, const float* __restrict__ tmv,
                            const float* __restrict__ tmr,
                            unsigned short* __restrict__ xs1, unsigned short* __restrict__ xs2,
                            unsigned short* __restrict__ WK1H, unsigned short* __restrict__ WK2H,
                            unsigned short* __restrict__ WVRH, unsigned short* __restrict__ WOH) {
  int bid = blockIdx.x;
  if (bid < 16384) {
    int i = bid * 256 + threadIdx.x;   // float4 index
    const int HV = H_DIM / 4;
    int m = i / HV;
    int t = m & (T_DIM - 1);
    float4 cur = reinterpret_cast<const float4*>(x)[i];
    float4 prev = make_float4(0.f, 0.f, 0.f, 0.f);
    if (t > 0) prev = reinterpret_cast<const float4*>(x)[i - HV];
    float s[4] = {cur.x + prev.x, cur.y + prev.y, cur.z + prev.z, cur.w + prev.w};
    unsigned short a1[4], a2[4];
#pragma unroll
    for (int q = 0; q < 4; ++q) {
      unsigned short h1 = f2h(s[q]);
      a1[q] = h1;
      a2[q] = f2h((s[q] - h2f(h1)) * 2048.0f);
    }
    reinterpret_cast<ushort4*>(xs1)[i] = make_ushort4(a1[0], a1[1], a1[2], a1[3]);
    reinterpret_cast<ushort4*>(xs2)[i] = make_ushort4(a2[0], a2[1], a2[2], a2[3]);
  } else {
    int i = (bid - 16384) * 256 + threadIdx.x;
    int j = i & (H_DIM - 1);
    float wk = Wkey[i] * tmk[j];
    unsigned short k1 = f2h(wk);
    WK1H[i] = k1;
    WK2H[i] = f2h((wk - h2f(k1)) * 2048.0f);
    WVRH[i] = f2h(Wval[i] * tmv[j]);
    WVRH[H_DIM * H_DIM + i] = f2h(Wrec[i] * tmr[j]);
    WOH[i] = f2h(Wout[i]);
  }
}

// ------------------------- shared helpers -------------------------
#define GBAR() do { asm volatile("" ::: "memory"); __builtin_amdgcn_sched_barrier(0); \
                    __builtin_amdgcn_s_barrier(); \
                    __builtin_amdgcn_sched_barrier(0); asm volatile("" ::: "memory"); } while (0)
#define WAIT_VM6() asm volatile("s_waitcnt vmcnt(6)" ::: "memory")
#define WAIT_VM4() asm volatile("s_waitcnt vmcnt(4)" ::: "memory")
#define WAIT_VM0() asm volatile("s_waitcnt vmcnt(0)" ::: "memory")

__device__ __forceinline__ f32x4 mma_h(short8 a, short8 b, f32x4 c) {
  return __builtin_amdgcn_mfma_f32_16x16x32_f16(
      __builtin_bit_cast(half8, a), __builtin_bit_cast(half8, b), c, 0, 0, 0);
}

// stage 128 rows x 32 cols (8KB): 1 load/thread; linear LDS, inverse-swz source
__device__ __forceinline__ void stage_r128(const unsigned short* base, int rowoff, int kt,
                                           unsigned dst, int wid, int lane,
                                           unsigned char* smem) {
  int row = wid * 16 + (lane >> 2);
  int col8 = (lane & 3) ^ ((row >> 1) & 3);
  const unsigned short* src = base + (size_t)(rowoff + row) * 1024 + kt * 32 + col8 * 8;
  __builtin_amdgcn_global_load_lds(
      (const __attribute__((address_space(1))) void*)src,
      (__attribute__((address_space(3))) void*)(smem + dst + wid * 1024), 16, 0, 0);
}
// stage 256 rows x 32 cols (16KB): 2 loads/thread
__device__ __forceinline__ void stage_r256(const unsigned short* base, int rowoff, int kt,
                                           unsigned dst, int wid, int lane,
                                           unsigned char* smem) {
#pragma unroll
  for (int i = 0; i < 2; ++i) {
    int row = wid * 32 + i * 16 + (lane >> 2);
    int col8 = (lane & 3) ^ ((row >> 1) & 3);
    const unsigned short* src = base + (size_t)(rowoff + row) * 1024 + kt * 32 + col8 * 8;
    __builtin_amdgcn_global_load_lds(
        (const __attribute__((address_space(1))) void*)src,
        (__attribute__((address_space(3))) void*)(smem + dst + wid * 2048 + i * 1024), 16, 0, 0);
  }
}
__device__ __forceinline__ short8 frag_ld2(const unsigned char* smem, unsigned rbase,
                                           int row, int kg) {
  return *reinterpret_cast<const short8*>(smem + rbase + row * 64 + ((kg ^ ((row >> 1) & 3)) * 16));
}

// ============ k-role: 128x256 tile, 3-combo fp32-emulated GEMM, 2 phases/tile ============
// k ~= A1B1 + 2^-11*(A1B2 + A2B1).  BK=32, 3-slot LDS ring, 2-tile lead, vmcnt(6)/tile.
__device__ void gemm_k_body(const unsigned short* __restrict__ A1,
                            const unsigned short* __restrict__ A2,
                            const unsigned short* __restrict__ B1,
                            const unsigned short* __restrict__ B2,
                            float* __restrict__ C, int bid, unsigned char* smem) {
  const int tid = threadIdx.x;
  const int wid = tid >> 6;
  const int lane = tid & 63;
  const int wm = wid >> 2;   // 0..1 -> 64 rows each
  const int wn = wid & 3;    // 0..3 -> 64 cols each
  const int frow = lane & 15;
  const int kg = lane >> 4;
  const int swz = (bid & 7) * 64 + (bid >> 3);   // nwg=512, bijective
  const int brow = (swz >> 2) << 7;   // 128-row tile
  const int bcol = (swz & 3) << 8;    // 256-col tile

  f32x4 acc0[4][4], acc1[4][4];
#pragma unroll
  for (int f = 0; f < 4; ++f)
#pragma unroll
    for (int c = 0; c < 4; ++c) {
      acc0[f][c] = (f32x4){0.f, 0.f, 0.f, 0.f};
      acc1[f][c] = (f32x4){0.f, 0.f, 0.f, 0.f};
    }

  const int NT = 32;  // K=1024 / BK=32
#pragma unroll
  for (int t0 = 0; t0 < 2; ++t0) {
    unsigned sb = t0 * 49152u;
    stage_r128(A1, brow, t0, sb + 0u, wid, lane, smem);
    stage_r128(A2, brow, t0, sb + 8192u, wid, lane, smem);
    stage_r256(B1, bcol, t0, sb + 16384u, wid, lane, smem);
    stage_r256(B2, bcol, t0, sb + 32768u, wid, lane, smem);
  }
  WAIT_VM6();
  GBAR();

  for (int t = 0; t < NT; ++t) {
    unsigned sb = (unsigned)(t % 3) * 49152u;
    unsigned st = (unsigned)((t + 2) % 3) * 49152u;
    const bool stg = (t + 2 < NT);
    short8 a1[4], a2[4], b1[4], b2[4];
    // ---- P0: read a1,b1,b2 (12); stage A1,A2(t+2); 32 MFMA ----
#pragma unroll
    for (int f = 0; f < 4; ++f) a1[f] = frag_ld2(smem, sb + 0u, wm * 64 + f * 16 + frow, kg);
#pragma unroll
    for (int c = 0; c < 4; ++c) b1[c] = frag_ld2(smem, sb + 16384u, wn * 64 + c * 16 + frow, kg);
#pragma unroll
    for (int c = 0; c < 4; ++c) b2[c] = frag_ld2(smem, sb + 32768u, wn * 64 + c * 16 + frow, kg);
    if (stg) {
      stage_r128(A1, brow, t + 2, st + 0u, wid, lane, smem);
      stage_r128(A2, brow, t + 2, st + 8192u, wid, lane, smem);
    }
    GBAR();
    __builtin_amdgcn_s_setprio(1);
#pragma unroll
    for (int f = 0; f < 4; ++f)
#pragma unroll
      for (int c = 0; c < 4; ++c)
        acc0[f][c] = mma_h(a1[f], b1[c], acc0[f][c]);
#pragma unroll
    for (int f = 0; f < 4; ++f)
#pragma unroll
      for (int c = 0; c < 4; ++c)
        acc1[f][c] = mma_h(a1[f], b2[c], acc1[f][c]);
    __builtin_amdgcn_s_setprio(0);
    GBAR();
    // ---- P1: read a2 (4); stage B1,B2(t+2); counted wait; 16 MFMA ----
#pragma unroll
    for (int f = 0; f < 4; ++f) a2[f] = frag_ld2(smem, sb + 8192u, wm * 64 + f * 16 + frow, kg);
    if (stg) {
      stage_r256(B1, bcol, t + 2, st + 16384u, wid, lane, smem);
      stage_r256(B2, bcol, t + 2, st + 32768u, wid, lane, smem);
      WAIT_VM6();
    } else {
      WAIT_VM0();  // tail: remaining loads must land (nothing newer to count against)
    }
    GBAR();
    __builtin_amdgcn_s_setprio(1);
#pragma unroll
    for (int f = 0; f < 4; ++f)
#pragma unroll
      for (int c = 0; c < 4; ++c)
        acc1[f][c] = mma_h(a2[f], b1[c], acc1[f][c]);
    __builtin_amdgcn_s_setprio(0);
    GBAR();
  }
  WAIT_VM0();

  // out = acc0 + 2^-11*acc1; C/D layout col=lane&15, row=(lane>>4)*4+q
#pragma unroll
  for (int f = 0; f < 4; ++f) {
    int r0 = brow + wm * 64 + f * 16 + kg * 4;
#pragma unroll
    for (int c = 0; c < 4; ++c) {
      int cc = bcol + wn * 64 + c * 16 + frow;
#pragma unroll
      for (int q = 0; q < 4; ++q)
        C[(size_t)(r0 + q) * H_DIM + cc] =
            fmaf(0.00048828125f, acc1[f][c][q], acc0[f][c][q]);
    }
  }
}

// ===== vr-role: 256x256 tile, BK=32 ring-3 (32KB/slot), 2 phases/tile, vmcnt(4)/tile =====
// Same K-chunk MFMA order as before -> bitwise-identical numerics; fill/drain 20% -> 6%.
__device__ void gemm_vr_body(const unsigned short* __restrict__ Ag,
                             const unsigned short* __restrict__ Bg,
                             unsigned short* __restrict__ C, int bid,
                             unsigned char* smem) {
  const int tid = threadIdx.x;
  const int wid = tid >> 6;
  const int lane = tid & 63;
  const int wm = wid >> 2;   // 0..1 -> 128 rows each
  const int wn = wid & 3;    // 0..3 -> 64 cols each
  const int frow = lane & 15;
  const int kg = lane >> 4;
  const int swz = (bid & 7) * 64 + (bid >> 3);   // nwg=512
  const int brow = (swz >> 3) << 8;   // 64 row-blocks
  const int bcol = (swz & 7) << 8;    // 8 col-blocks (N=2048)

  f32x4 acc[8][4];
#pragma unroll
  for (int f = 0; f < 8; ++f)
#pragma unroll
    for (int c = 0; c < 4; ++c)
      acc[f][c] = (f32x4){0.f, 0.f, 0.f, 0.f};

  const int NT = 32;  // K=1024 / BK=32
#pragma unroll
  for (int t0 = 0; t0 < 2; ++t0) {
    unsigned sb = t0 * 32768u;
    stage_r256(Ag, brow, t0, sb + 0u, wid, lane, smem);
    stage_r256(Bg, bcol, t0, sb + 16384u, wid, lane, smem);
  }
  WAIT_VM4();
  GBAR();

  for (int t = 0; t < NT; ++t) {
    unsigned sb = (unsigned)(t % 3) * 32768u;
    unsigned st = (unsigned)((t + 2) % 3) * 32768u;
    const bool stg = (t + 2 < NT);
    short8 a[4], b[4];
    // ---- P0: read a0-3,b0-3 (8); stage A(t+2); 16 MFMA ----
#pragma unroll
    for (int f = 0; f < 4; ++f) a[f] = frag_ld2(smem, sb + 0u, wm * 128 + f * 16 + frow, kg);
#pragma unroll
    for (int c = 0; c < 4; ++c) b[c] = frag_ld2(smem, sb + 16384u, wn * 64 + c * 16 + frow, kg);
    if (stg) stage_r256(Ag, brow, t + 2, st + 0u, wid, lane, smem);
    GBAR();
    __builtin_amdgcn_s_setprio(1);
#pragma unroll
    for (int f = 0; f < 4; ++f)
#pragma unroll
      for (int c = 0; c < 4; ++c)
        acc[f][c] = mma_h(a[f], b[c], acc[f][c]);
    __builtin_amdgcn_s_setprio(0);
    GBAR();
    // ---- P1: read a4-7 (4); stage B(t+2); counted wait; 16 MFMA ----
#pragma unroll
    for (int f = 0; f < 4; ++f) a[f] = frag_ld2(smem, sb + 0u, wm * 128 + (f + 4) * 16 + frow, kg);
    if (stg) {
      stage_r256(Bg, bcol, t + 2, st + 16384u, wid, lane, smem);
      WAIT_VM4();
    } else {
      WAIT_VM0();
    }
    GBAR();
    __builtin_amdgcn_s_setprio(1);
#pragma unroll
    for (int f = 0; f < 4; ++f)
#pragma unroll
      for (int c = 0; c < 4; ++c)
        acc[f + 4][c] = mma_h(a[f], b[c], acc[f + 4][c]);
    __builtin_amdgcn_s_setprio(0);
    GBAR();
  }
  WAIT_VM0();

#pragma unroll
  for (int f = 0; f < 8; ++f) {
    int r0 = brow + wm * 128 + f * 16 + kg * 4;
#pragma unroll
    for (int c = 0; c < 4; ++c) {
      int cc = bcol + wn * 64 + c * 16 + frow;
#pragma unroll
      for (int q = 0; q < 4; ++q)
        C[(size_t)(r0 + q) * 2048 + cc] = f2h(acc[f][c][q]);
    }
  }
}

// fused front dispatch: blocks 0..511 compute k (fp32 -> Ck), 512..1023 compute v|r (fp16 -> Cvr)
__global__ __launch_bounds__(512, 2) void front_kernel(
    const unsigned short* __restrict__ XS1, const unsigned short* __restrict__ XS2,
    const unsigned short* __restrict__ WK1, const unsigned short* __restrict__ WK2,
    const unsigned short* __restrict__ WVR,
    float* __restrict__ Ck, unsigned short* __restrict__ Cvr) {
  __shared__ __attribute__((aligned(16))) unsigned char smem[147456];
  int bid = blockIdx.x;
  if (bid < 512)
    gemm_k_body(XS1, XS2, WK1, WK2, Ck, bid, smem);
  else
    gemm_vr_body(XS1, WVR, Cvr, bid - 512, smem);
}

// ===== Po: 256x256 tile, BK=32 ring-3, 2 phases/tile, vmcnt(4)/tile, fp32 out + bias =====
__global__ __launch_bounds__(512, 2) void gemm_o_kernel(const unsigned short* __restrict__ Ag,
                                                        const unsigned short* __restrict__ Bg,
                                                        float* __restrict__ C,
                                                        const float* __restrict__ bias) {
  __shared__ __attribute__((aligned(16))) unsigned char smem[98304];  // 3 x 32KB
  const int tid = threadIdx.x;
  const int wid = tid >> 6;
  const int lane = tid & 63;
  const int wm = wid >> 2;
  const int wn = wid & 3;
  const int frow = lane & 15;
  const int kg = lane >> 4;
  const int bid = blockIdx.x;
  const int swz = (bid & 7) * 32 + (bid >> 3);   // nwg=256, bijective
  const int brow = (swz >> 2) << 8;   // 64 row-blocks
  const int bcol = (swz & 3) << 8;    // 4 col-blocks (N=1024)

  f32x4 acc[8][4];
#pragma unroll
  for (int f = 0; f < 8; ++f)
#pragma unroll
    for (int c = 0; c < 4; ++c)
      acc[f][c] = (f32x4){0.f, 0.f, 0.f, 0.f};

  const int NT = 32;
#pragma unroll
  for (int t0 = 0; t0 < 2; ++t0) {
    unsigned sb = t0 * 32768u;
    stage_r256(Ag, brow, t0, sb + 0u, wid, lane, smem);
    stage_r256(Bg, bcol, t0, sb + 16384u, wid, lane, smem);
  }
  WAIT_VM4();
  GBAR();

  for (int t = 0; t < NT; ++t) {
    unsigned sb = (unsigned)(t % 3) * 32768u;
    unsigned st = (unsigned)((t + 2) % 3) * 32768u;
    const bool stg = (t + 2 < NT);
    short8 a[4], b[4];
#pragma unroll
    for (int f = 0; f < 4; ++f) a[f] = frag_ld2(smem, sb + 0u, wm * 128 + f * 16 + frow, kg);
#pragma unroll
    for (int c = 0; c < 4; ++c) b[c] = frag_ld2(smem, sb + 16384u, wn * 64 + c * 16 + frow, kg);
    if (stg) stage_r256(Ag, brow, t + 2, st + 0u, wid, lane, smem);
    GBAR();
    __builtin_amdgcn_s_setprio(1);
#pragma unroll
    for (int f = 0; f < 4; ++f)
#pragma unroll
      for (int c = 0; c < 4; ++c)
        acc[f][c] = mma_h(a[f], b[c], acc[f][c]);
    __builtin_amdgcn_s_setprio(0);
    GBAR();
#pragma unroll
    for (int f = 0; f < 4; ++f) a[f] = frag_ld2(smem, sb + 0u, wm * 128 + (f + 4) * 16 + frow, kg);
    if (stg) {
      stage_r256(Bg, bcol, t + 2, st + 16384u, wid, lane, smem);
      WAIT_VM4();
    } else {
      WAIT_VM0();
    }
    GBAR();
    __builtin_amdgcn_s_setprio(1);
#pragma unroll
    for (int f = 0; f < 4; ++f)
#pragma unroll
      for (int c = 0; c < 4; ++c)
        acc[f + 4][c] = mma_h(a[f], b[c], acc[f + 4][c]);
    __builtin_amdgcn_s_setprio(0);
    GBAR();
  }
  WAIT_VM0();

#pragma unroll
  for (int f = 0; f < 8; ++f) {
    int r0 = brow + wm * 128 + f * 16 + kg * 4;
#pragma unroll
    for (int c = 0; c < 4; ++c) {
      int cc = bcol + wn * 64 + c * 16 + frow;
      float bb = bias[cc];
#pragma unroll
      for (int q = 0; q < 4; ++q)
        C[(size_t)(r0 + q) * H_DIM + cc] = acc[f][c][q] + bb;
    }
  }
}

// ---------------- WKV scan: fp64 state + fp32 __expf; ILP-2, C=64/W=48, clamped ----------------
__global__ void wkv_scan_kernel(const float* __restrict__ kbuf,
                                const unsigned short* __restrict__ vrbuf,
                                const float* __restrict__ tdec,
                                unsigned short* __restrict__ rwh) {
  const int h = (blockIdx.x * 64 + threadIdx.x) * 2;
  const int chunk = blockIdx.y;
  const int b = blockIdx.z;
  const int t0 = chunk * SCAN_C;
  int tstart = t0 - SCAN_W;
  if (tstart < 0) tstart = 0;
  const int tend = t0 + SCAN_C;
  double num0, den0, num1, den1;
  if (tstart == 0) { num0 = num1 = 1.0; den0 = den1 = 1.0; }
  else             { num0 = num1 = 0.0; den0 = den1 = 0.0; }
  const double w0 = (double)tdec[h];
  const double w1 = (double)tdec[h + 1];
  size_t ik = ((size_t)b * T_DIM + tstart) * H_DIM + h;
  size_t iv = ((size_t)b * T_DIM + tstart) * 2048 + h;
  float2 kc = *reinterpret_cast<const float2*>(kbuf + ik);
  unsigned int vc = *reinterpret_cast<const unsigned int*>(vrbuf + iv);
  unsigned int rc = *reinterpret_cast<const unsigned int*>(vrbuf + iv + 1024);
  for (int t = tstart; t < tend; ++t) {
    size_t adv = (t + 1 < tend) ? 1 : 0;
    float2 kn = *reinterpret_cast<const float2*>(kbuf + ik + adv * H_DIM);
    unsigned int vn = *reinterpret_cast<const unsigned int*>(vrbuf + iv + adv * 2048);
    unsigned int rn = *reinterpret_cast<const unsigned int*>(vrbuf + iv + adv * 2048 + 1024);
    if (t >= t0) {
      double p0 = w0 * (double)kc.x, p1 = w1 * (double)kc.y;
      float o0 = (float)fma(p0, den0, num0) / (float)(den0 + p0);
      float o1 = (float)fma(p1, den1, num1) / (float)(den1 + p1);
      float rr0 = 1.0f / (1.0f + __expf(-h2f((unsigned short)(rc & 0xffffu))));
      float rr1 = 1.0f / (1.0f + __expf(-h2f((unsigned short)(rc >> 16))));
      unsigned int wout = (unsigned int)f2h(rr0 * o0) | ((unsigned int)f2h(rr1 * o1) << 16);
      *reinterpret_cast<unsigned int*>(rwh + ik) = wout;
    }
    float ek0f = __expf(kc.x);
    float ek1f = __expf(kc.y);
    num0 = fma(w0, num0, (double)(ek0f * h2f((unsigned short)(vc & 0xffffu))));
    den0 = fma(w0, den0, (double)ek0f);
    num1 = fma(w1, num1, (double)(ek1f * h2f((unsigned short)(vc >> 16))));
    den1 = fma(w1, den1, (double)ek1f);
    kc = kn; vc = vn; rc = rn;
    ik += H_DIM; iv += 2048;
  }
}

// -------------------------------- host --------------------------------
extern "C" void kernel_launch(void* const* d_in, const int* in_sizes, int n_in,
                              void* d_out, int out_size, void* d_ws, size_t ws_size,
                              hipStream_t stream) {
  const float* x    = (const float*)d_in[0];
  const float* tdec = (const float*)d_in[1];
  const float* tmk  = (const float*)d_in[2];
  const float* tmv  = (const float*)d_in[3];
  const float* tmr  = (const float*)d_in[4];
  const float* Wrec = (const float*)d_in[5];
  const float* Wkey = (const float*)d_in[6];
  const float* Wval = (const float*)d_in[7];
  const float* Wout = (const float*)d_in[8];
  const float* bout = (const float*)d_in[9];
  float* out = (float*)d_out;
  unsigned char* ws = (unsigned char*)d_ws;

  const size_t W2 = (size_t)H_DIM * H_DIM * 2;       // 2MB per fp16 weight
  const size_t BF_FULL = (size_t)M_DIM * H_DIM * 2;  // 32MB fp16 [M,H]
  const size_t NEED = 2 * BF_FULL + 2 * BF_FULL + 5 * W2;  // 138MB
  if (ws_size < NEED) return;

  size_t off = 0;
  unsigned short* XS1H = (unsigned short*)(ws + off); off += BF_FULL;
  unsigned short* XS2H = (unsigned short*)(ws + off); off += BF_FULL;
  unsigned short* VR   = (unsigned short*)(ws + off); off += 2 * BF_FULL;  // [M,2048] fp16
  unsigned short* WK1H = (unsigned short*)(ws + off); off += W2;
  unsigned short* WK2H = (unsigned short*)(ws + off); off += W2;
  unsigned short* WVRH = (unsigned short*)(ws + off); off += 2 * W2;       // [2048,1024] fp16
  unsigned short* WOH  = (unsigned short*)(ws + off); off += W2;

  // fused prep: xs split + weight prep in one dispatch
  prep_kernel<<<dim3(16384 + 4096), dim3(256), 0, stream>>>(
      x, Wrec, Wkey, Wval, Wout, tmk, tmv, tmr, XS1H, XS2H, WK1H, WK2H, WVRH, WOH);

  // fused front: k (fp32 -> d_out) + v|r (fp16 -> VR) in one 1024-block dispatch
  front_kernel<<<dim3(1024), dim3(512), 0, stream>>>(
      XS1H, XS2H, WK1H, WK2H, WVRH, out, VR);

  // WKV scan (ILP-2, C=64, fp32 exp); rw (fp16) reuses XS1H (dead after front)
  unsigned short* RWH = XS1H;
  wkv_scan_kernel<<<dim3(H_DIM / 128, T_DIM / SCAN_C, B_DIM), dim3(64), 0, stream>>>(
      out, VR, tdec, RWH);

  // final projection + bias -> d_out fp32 (BK=32 ring-3, 256 blocks)
  gemm_o_kernel<<<dim3(256), dim3(512), 0, stream>>>(RWH, WOH, out, bout);
}

// Round 15
// 299.657 us; speedup vs baseline: 1.0140x; 1.0140x over previous
//
#include <hip/hip_runtime.h>

#define H_DIM 1024
#define T_DIM 4096
#define B_DIM 4
#define M_DIM (B_DIM * T_DIM)   // 16384
#define SCAN_C 64
#define SCAN_W 48

typedef __attribute__((ext_vector_type(8))) short short8;
typedef __attribute__((ext_vector_type(4))) float f32x4;
typedef _Float16 half8 __attribute__((ext_vector_type(8)));

__device__ __forceinline__ unsigned short f2h(float f) {
  _Float16 h = (_Float16)f;
  return __builtin_bit_cast(unsigned short, h);
}
__device__ __forceinline__ float h2f(unsigned short u) {
  return (float)__builtin_bit_cast(_Float16, u);
}

// ------- fused prep: xs split (blocks 0..16383) + weight prep (blocks 16384..20479) -------
__global__ void prep_kernel(const float* __restrict__ x,
                            const float* __restrict__ Wrec, const float* __restrict__ Wkey,
                            const float* __restrict__ Wval, const float* __restrict__ Wout,
                            const float* __restrict__ tmk, const float* __restrict__ tmv,
                            const float* __restrict__ tmr,
                            unsigned short* __restrict__ xs1, unsigned short* __restrict__ xs2,
                            unsigned short* __restrict__ WK1H, unsigned short* __restrict__ WK2H,
                            unsigned short* __restrict__ WVRH, unsigned short* __restrict__ WOH) {
  int bid = blockIdx.x;
  if (bid < 16384) {
    int i = bid * 256 + threadIdx.x;   // float4 index
    const int HV = H_DIM / 4;
    int m = i / HV;
    int t = m & (T_DIM - 1);
    float4 cur = reinterpret_cast<const float4*>(x)[i];
    float4 prev = make_float4(0.f, 0.f, 0.f, 0.f);
    if (t > 0) prev = reinterpret_cast<const float4*>(x)[i - HV];
    float s[4] = {cur.x + prev.x, cur.y + prev.y, cur.z + prev.z, cur.w + prev.w};
    unsigned short a1[4], a2[4];
#pragma unroll
    for (int q = 0; q < 4; ++q) {
      unsigned short h1 = f2h(s[q]);
      a1[q] = h1;
      a2[q] = f2h((s[q] - h2f(h1)) * 2048.0f);
    }
    reinterpret_cast<ushort4*>(xs1)[i] = make_ushort4(a1[0], a1[1], a1[2], a1[3]);
    reinterpret_cast<ushort4*>(xs2)[i] = make_ushort4(a2[0], a2[1], a2[2], a2[3]);
  } else {
    int i = (bid - 16384) * 256 + threadIdx.x;
    int j = i & (H_DIM - 1);
    float wk = Wkey[i] * tmk[j];
    unsigned short k1 = f2h(wk);
    WK1H[i] = k1;
    WK2H[i] = f2h((wk - h2f(k1)) * 2048.0f);
    WVRH[i] = f2h(Wval[i] * tmv[j]);
    WVRH[H_DIM * H_DIM + i] = f2h(Wrec[i] * tmr[j]);
    WOH[i] = f2h(Wout[i]);
  }
}

// ------------------------- shared helpers -------------------------
#define GBAR() do { asm volatile("" ::: "memory"); __builtin_amdgcn_sched_barrier(0); \
                    __builtin_amdgcn_s_barrier(); \
                    __builtin_amdgcn_sched_barrier(0); asm volatile("" ::: "memory"); } while (0)
#define WAIT_VM6() asm volatile("s_waitcnt vmcnt(6)" ::: "memory")
#define WAIT_VM0() asm volatile("s_waitcnt vmcnt(0)" ::: "memory")

__device__ __forceinline__ f32x4 mma_h(short8 a, short8 b, f32x4 c) {
  return __builtin_amdgcn_mfma_f32_16x16x32_f16(
      __builtin_bit_cast(half8, a), __builtin_bit_cast(half8, b), c, 0, 0, 0);
}

// stage 128 rows x 32 cols (8KB): 1 load/thread; linear LDS, inverse-swz source
__device__ __forceinline__ void stage_r128(const unsigned short* base, int rowoff, int kt,
                                           unsigned dst, int wid, int lane,
                                           unsigned char* smem) {
  int row = wid * 16 + (lane >> 2);
  int col8 = (lane & 3) ^ ((row >> 1) & 3);
  const unsigned short* src = base + (size_t)(rowoff + row) * 1024 + kt * 32 + col8 * 8;
  __builtin_amdgcn_global_load_lds(
      (const __attribute__((address_space(1))) void*)src,
      (__attribute__((address_space(3))) void*)(smem + dst + wid * 1024), 16, 0, 0);
}
// stage 256 rows x 32 cols (16KB): 2 loads/thread
__device__ __forceinline__ void stage_r256(const unsigned short* base, int rowoff, int kt,
                                           unsigned dst, int wid, int lane,
                                           unsigned char* smem) {
#pragma unroll
  for (int i = 0; i < 2; ++i) {
    int row = wid * 32 + i * 16 + (lane >> 2);
    int col8 = (lane & 3) ^ ((row >> 1) & 3);
    const unsigned short* src = base + (size_t)(rowoff + row) * 1024 + kt * 32 + col8 * 8;
    __builtin_amdgcn_global_load_lds(
        (const __attribute__((address_space(1))) void*)src,
        (__attribute__((address_space(3))) void*)(smem + dst + wid * 2048 + i * 1024), 16, 0, 0);
  }
}
__device__ __forceinline__ short8 frag_ld2(const unsigned char* smem, unsigned rbase,
                                           int row, int kg) {
  return *reinterpret_cast<const short8*>(smem + rbase + row * 64 + ((kg ^ ((row >> 1) & 3)) * 16));
}

// ============ k-role: 128x256 tile, 3-combo fp32-emulated GEMM, 2 phases/tile ============
// k ~= A1B1 + 2^-11*(A1B2 + A2B1).  BK=32, 3-slot LDS ring, 2-tile lead, vmcnt(6)/tile.
// R9 phase split (best measured): P0 = 12 reads + A-stage + 32 MFMA; P1 = 4 reads + B-stage + 16 MFMA.
__device__ void gemm_k_body(const unsigned short* __restrict__ A1,
                            const unsigned short* __restrict__ A2,
                            const unsigned short* __restrict__ B1,
                            const unsigned short* __restrict__ B2,
                            float* __restrict__ C, int bid, unsigned char* smem) {
  const int tid = threadIdx.x;
  const int wid = tid >> 6;
  const int lane = tid & 63;
  const int wm = wid >> 2;   // 0..1 -> 64 rows each
  const int wn = wid & 3;    // 0..3 -> 64 cols each
  const int frow = lane & 15;
  const int kg = lane >> 4;
  const int swz = (bid & 7) * 64 + (bid >> 3);   // nwg=512, bijective
  const int brow = (swz >> 2) << 7;   // 128-row tile
  const int bcol = (swz & 3) << 8;    // 256-col tile

  f32x4 acc0[4][4], acc1[4][4];
#pragma unroll
  for (int f = 0; f < 4; ++f)
#pragma unroll
    for (int c = 0; c < 4; ++c) {
      acc0[f][c] = (f32x4){0.f, 0.f, 0.f, 0.f};
      acc1[f][c] = (f32x4){0.f, 0.f, 0.f, 0.f};
    }

  const int NT = 32;  // K=1024 / BK=32
#pragma unroll
  for (int t0 = 0; t0 < 2; ++t0) {
    unsigned sb = t0 * 49152u;
    stage_r128(A1, brow, t0, sb + 0u, wid, lane, smem);
    stage_r128(A2, brow, t0, sb + 8192u, wid, lane, smem);
    stage_r256(B1, bcol, t0, sb + 16384u, wid, lane, smem);
    stage_r256(B2, bcol, t0, sb + 32768u, wid, lane, smem);
  }
  WAIT_VM6();
  GBAR();

  for (int t = 0; t < NT; ++t) {
    unsigned sb = (unsigned)(t % 3) * 49152u;
    unsigned st = (unsigned)((t + 2) % 3) * 49152u;
    const bool stg = (t + 2 < NT);
    short8 a1[4], a2[4], b1[4], b2[4];
    // ---- P0: read a1,b1,b2 (12); stage A1,A2(t+2); 32 MFMA ----
#pragma unroll
    for (int f = 0; f < 4; ++f) a1[f] = frag_ld2(smem, sb + 0u, wm * 64 + f * 16 + frow, kg);
#pragma unroll
    for (int c = 0; c < 4; ++c) b1[c] = frag_ld2(smem, sb + 16384u, wn * 64 + c * 16 + frow, kg);
#pragma unroll
    for (int c = 0; c < 4; ++c) b2[c] = frag_ld2(smem, sb + 32768u, wn * 64 + c * 16 + frow, kg);
    if (stg) {
      stage_r128(A1, brow, t + 2, st + 0u, wid, lane, smem);
      stage_r128(A2, brow, t + 2, st + 8192u, wid, lane, smem);
    }
    GBAR();
    __builtin_amdgcn_s_setprio(1);
#pragma unroll
    for (int f = 0; f < 4; ++f)
#pragma unroll
      for (int c = 0; c < 4; ++c)
        acc0[f][c] = mma_h(a1[f], b1[c], acc0[f][c]);
#pragma unroll
    for (int f = 0; f < 4; ++f)
#pragma unroll
      for (int c = 0; c < 4; ++c)
        acc1[f][c] = mma_h(a1[f], b2[c], acc1[f][c]);
    __builtin_amdgcn_s_setprio(0);
    GBAR();
    // ---- P1: read a2 (4); stage B1,B2(t+2); counted wait; 16 MFMA ----
#pragma unroll
    for (int f = 0; f < 4; ++f) a2[f] = frag_ld2(smem, sb + 8192u, wm * 64 + f * 16 + frow, kg);
    if (stg) {
      stage_r256(B1, bcol, t + 2, st + 16384u, wid, lane, smem);
      stage_r256(B2, bcol, t + 2, st + 32768u, wid, lane, smem);
      WAIT_VM6();
    } else {
      WAIT_VM0();  // tail: remaining loads must land (nothing newer to count against)
    }
    GBAR();
    __builtin_amdgcn_s_setprio(1);
#pragma unroll
    for (int f = 0; f < 4; ++f)
#pragma unroll
      for (int c = 0; c < 4; ++c)
        acc1[f][c] = mma_h(a2[f], b1[c], acc1[f][c]);
    __builtin_amdgcn_s_setprio(0);
    GBAR();
  }
  WAIT_VM0();

  // out = acc0 + 2^-11*acc1; C/D layout col=lane&15, row=(lane>>4)*4+q
#pragma unroll
  for (int f = 0; f < 4; ++f) {
    int r0 = brow + wm * 64 + f * 16 + kg * 4;
#pragma unroll
    for (int c = 0; c < 4; ++c) {
      int cc = bcol + wn * 64 + c * 16 + frow;
#pragma unroll
      for (int q = 0; q < 4; ++q)
        C[(size_t)(r0 + q) * H_DIM + cc] =
            fmaf(0.00048828125f, acc1[f][c][q], acc0[f][c][q]);
    }
  }
}

// ============ vr-role: 256x256 8-phase fp16 GEMM, N=2048, fp16 out ============
__device__ __forceinline__ void stage_half(const unsigned short* base, int rowoff,
                                           int ktp, int kk, int slot,
                                           int wid, int lane, unsigned char* smem) {
#pragma unroll
  for (int i = 0; i < 2; ++i) {
    int row = wid * 32 + i * 16 + (lane >> 2);
    int kcol8 = (lane & 3) ^ ((row >> 1) & 3);
    const unsigned short* src = base + (size_t)(rowoff + row) * 1024
                                + ktp * 64 + kk * 32 + kcol8 * 8;
    unsigned int doff = (unsigned int)(slot * 16384 + wid * 2048 + i * 1024);
    __builtin_amdgcn_global_load_lds(
        (const __attribute__((address_space(1))) void*)src,
        (__attribute__((address_space(3))) void*)(smem + doff), 16, 0, 0);
  }
}
__device__ __forceinline__ short8 frag_ld(const unsigned char* smem, int slot, int row, int kg) {
  int byte = slot * 16384 + row * 64 + ((kg ^ ((row >> 1) & 3)) * 16);
  return *reinterpret_cast<const short8*>(smem + byte);
}

__device__ void gemm_vr_body(const unsigned short* __restrict__ Ag,
                             const unsigned short* __restrict__ Bg,
                             unsigned short* __restrict__ C, int bid,
                             unsigned char* smem) {
  const int tid = threadIdx.x;
  const int wid = tid >> 6;
  const int lane = tid & 63;
  const int wm = wid >> 2;
  const int wn = wid & 3;
  const int frow = lane & 15;
  const int kg = lane >> 4;
  const int swz = (bid & 7) * 64 + (bid >> 3);   // nwg=512
  const int brow = (swz >> 3) << 8;   // 64 row-blocks
  const int bcol = (swz & 7) << 8;    // 8 col-blocks (N=2048)

  f32x4 acc[8][4];
#pragma unroll
  for (int f = 0; f < 8; ++f)
#pragma unroll
    for (int c = 0; c < 4; ++c)
      acc[f][c] = (f32x4){0.f, 0.f, 0.f, 0.f};

  const int NT = 16;
  stage_half(Ag, brow, 0, 0, 0, wid, lane, smem);
  stage_half(Bg, bcol, 0, 0, 1, wid, lane, smem);
  stage_half(Ag, brow, 0, 1, 2, wid, lane, smem);
  stage_half(Bg, bcol, 0, 1, 3, wid, lane, smem);
  stage_half(Ag, brow, 1, 0, 4, wid, lane, smem);
  stage_half(Bg, bcol, 1, 0, 5, wid, lane, smem);
  stage_half(Ag, brow, 1, 1, 6, wid, lane, smem);
  WAIT_VM6();
  GBAR();

  for (int t = 0; t < NT; ++t) {
    const int cur4 = (t & 1) * 4;
    const int nxt4 = cur4 ^ 4;
    short8 a[4], b[4];
#pragma unroll
    for (int f = 0; f < 4; ++f) a[f] = frag_ld(smem, cur4 + 0, wm * 128 + f * 16 + frow, kg);
#pragma unroll
    for (int c = 0; c < 4; ++c) b[c] = frag_ld(smem, cur4 + 1, wn * 64 + c * 16 + frow, kg);
    if (t + 1 < NT) stage_half(Bg, bcol, t + 1, 1, nxt4 + 3, wid, lane, smem);
    GBAR();
    __builtin_amdgcn_s_setprio(1);
#pragma unroll
    for (int f = 0; f < 4; ++f)
#pragma unroll
      for (int c = 0; c < 4; ++c)
        acc[f][c] = mma_h(a[f], b[c], acc[f][c]);
    __builtin_amdgcn_s_setprio(0);
    GBAR();
#pragma unroll
    for (int f = 0; f < 4; ++f) a[f] = frag_ld(smem, cur4 + 0, wm * 128 + (f + 4) * 16 + frow, kg);
    if (t + 2 < NT) stage_half(Ag, brow, t + 2, 0, cur4 + 0, wid, lane, smem);
    GBAR();
    __builtin_amdgcn_s_setprio(1);
#pragma unroll
    for (int f = 0; f < 4; ++f)
#pragma unroll
      for (int c = 0; c < 4; ++c)
        acc[f + 4][c] = mma_h(a[f], b[c], acc[f + 4][c]);
    __builtin_amdgcn_s_setprio(0);
    GBAR();
#pragma unroll
    for (int f = 0; f < 4; ++f) a[f] = frag_ld(smem, cur4 + 2, wm * 128 + f * 16 + frow, kg);
#pragma unroll
    for (int c = 0; c < 4; ++c) b[c] = frag_ld(smem, cur4 + 3, wn * 64 + c * 16 + frow, kg);
    if (t + 2 < NT) stage_half(Bg, bcol, t + 2, 0, cur4 + 1, wid, lane, smem);
    GBAR();
    __builtin_amdgcn_s_setprio(1);
#pragma unroll
    for (int f = 0; f < 4; ++f)
#pragma unroll
      for (int c = 0; c < 4; ++c)
        acc[f][c] = mma_h(a[f], b[c], acc[f][c]);
    __builtin_amdgcn_s_setprio(0);
    GBAR();
#pragma unroll
    for (int f = 0; f < 4; ++f) a[f] = frag_ld(smem, cur4 + 2, wm * 128 + (f + 4) * 16 + frow, kg);
    if (t + 2 < NT) stage_half(Ag, brow, t + 2, 1, cur4 + 2, wid, lane, smem);
    if (t + 2 < NT) { WAIT_VM6(); } else { WAIT_VM0(); }
    GBAR();
    __builtin_amdgcn_s_setprio(1);
#pragma unroll
    for (int f = 0; f < 4; ++f)
#pragma unroll
      for (int c = 0; c < 4; ++c)
        acc[f + 4][c] = mma_h(a[f], b[c], acc[f + 4][c]);
    __builtin_amdgcn_s_setprio(0);
    GBAR();
  }
  WAIT_VM0();

#pragma unroll
  for (int f = 0; f < 8; ++f) {
    int r0 = brow + wm * 128 + f * 16 + kg * 4;
#pragma unroll
    for (int c = 0; c < 4; ++c) {
      int cc = bcol + wn * 64 + c * 16 + frow;
#pragma unroll
      for (int q = 0; q < 4; ++q)
        C[(size_t)(r0 + q) * 2048 + cc] = f2h(acc[f][c][q]);
    }
  }
}

// fused front dispatch: blocks 0..511 compute k (fp32 -> Ck), 512..1023 compute v|r (fp16 -> Cvr)
__global__ __launch_bounds__(512, 2) void front_kernel(
    const unsigned short* __restrict__ XS1, const unsigned short* __restrict__ XS2,
    const unsigned short* __restrict__ WK1, const unsigned short* __restrict__ WK2,
    const unsigned short* __restrict__ WVR,
    float* __restrict__ Ck, unsigned short* __restrict__ Cvr) {
  __shared__ __attribute__((aligned(16))) unsigned char smem[147456];
  int bid = blockIdx.x;
  if (bid < 512)
    gemm_k_body(XS1, XS2, WK1, WK2, Ck, bid, smem);
  else
    gemm_vr_body(XS1, WVR, Cvr, bid - 512, smem);
}

// =================== Po: 256x256 8-phase fp16 GEMM, fp32 out + bias ===================
__global__ __launch_bounds__(512, 2) void gemm_o_kernel(const unsigned short* __restrict__ Ag,
                                                        const unsigned short* __restrict__ Bg,
                                                        float* __restrict__ C,
                                                        const float* __restrict__ bias) {
  __shared__ __attribute__((aligned(16))) unsigned char smem[131072];
  const int tid = threadIdx.x;
  const int wid = tid >> 6;
  const int lane = tid & 63;
  const int wm = wid >> 2;
  const int wn = wid & 3;
  const int frow = lane & 15;
  const int kg = lane >> 4;
  const int nwg = gridDim.x * gridDim.y;   // 256
  const int wg = blockIdx.y * gridDim.x + blockIdx.x;
  const int swz = (wg & 7) * (nwg >> 3) + (wg >> 3);
  const int brow = (swz / gridDim.x) << 8;
  const int bcol = (swz % gridDim.x) << 8;

  f32x4 acc[8][4];
#pragma unroll
  for (int f = 0; f < 8; ++f)
#pragma unroll
    for (int c = 0; c < 4; ++c)
      acc[f][c] = (f32x4){0.f, 0.f, 0.f, 0.f};

  const int NT = 16;
  stage_half(Ag, brow, 0, 0, 0, wid, lane, smem);
  stage_half(Bg, bcol, 0, 0, 1, wid, lane, smem);
  stage_half(Ag, brow, 0, 1, 2, wid, lane, smem);
  stage_half(Bg, bcol, 0, 1, 3, wid, lane, smem);
  stage_half(Ag, brow, 1, 0, 4, wid, lane, smem);
  stage_half(Bg, bcol, 1, 0, 5, wid, lane, smem);
  stage_half(Ag, brow, 1, 1, 6, wid, lane, smem);
  WAIT_VM6();
  GBAR();

  for (int t = 0; t < NT; ++t) {
    const int cur4 = (t & 1) * 4;
    const int nxt4 = cur4 ^ 4;
    short8 a[4], b[4];
#pragma unroll
    for (int f = 0; f < 4; ++f) a[f] = frag_ld(smem, cur4 + 0, wm * 128 + f * 16 + frow, kg);
#pragma unroll
    for (int c = 0; c < 4; ++c) b[c] = frag_ld(smem, cur4 + 1, wn * 64 + c * 16 + frow, kg);
    if (t + 1 < NT) stage_half(Bg, bcol, t + 1, 1, nxt4 + 3, wid, lane, smem);
    GBAR();
    __builtin_amdgcn_s_setprio(1);
#pragma unroll
    for (int f = 0; f < 4; ++f)
#pragma unroll
      for (int c = 0; c < 4; ++c)
        acc[f][c] = mma_h(a[f], b[c], acc[f][c]);
    __builtin_amdgcn_s_setprio(0);
    GBAR();
#pragma unroll
    for (int f = 0; f < 4; ++f) a[f] = frag_ld(smem, cur4 + 0, wm * 128 + (f + 4) * 16 + frow, kg);
    if (t + 2 < NT) stage_half(Ag, brow, t + 2, 0, cur4 + 0, wid, lane, smem);
    GBAR();
    __builtin_amdgcn_s_setprio(1);
#pragma unroll
    for (int f = 0; f < 4; ++f)
#pragma unroll
      for (int c = 0; c < 4; ++c)
        acc[f + 4][c] = mma_h(a[f], b[c], acc[f + 4][c]);
    __builtin_amdgcn_s_setprio(0);
    GBAR();
#pragma unroll
    for (int f = 0; f < 4; ++f) a[f] = frag_ld(smem, cur4 + 2, wm * 128 + f * 16 + frow, kg);
#pragma unroll
    for (int c = 0; c < 4; ++c) b[c] = frag_ld(smem, cur4 + 3, wn * 64 + c * 16 + frow, kg);
    if (t + 2 < NT) stage_half(Bg, bcol, t + 2, 0, cur4 + 1, wid, lane, smem);
    GBAR();
    __builtin_amdgcn_s_setprio(1);
#pragma unroll
    for (int f = 0; f < 4; ++f)
#pragma unroll
      for (int c = 0; c < 4; ++c)
        acc[f][c] = mma_h(a[f], b[c], acc[f][c]);
    __builtin_amdgcn_s_setprio(0);
    GBAR();
#pragma unroll
    for (int f = 0; f < 4; ++f) a[f] = frag_ld(smem, cur4 + 2, wm * 128 + (f + 4) * 16 + frow, kg);
    if (t + 2 < NT) stage_half(Ag, brow, t + 2, 1, cur4 + 2, wid, lane, smem);
    if (t + 2 < NT) { WAIT_VM6(); } else { WAIT_VM0(); }
    GBAR();
    __builtin_amdgcn_s_setprio(1);
#pragma unroll
    for (int f = 0; f < 4; ++f)
#pragma unroll
      for (int c = 0; c < 4; ++c)
        acc[f + 4][c] = mma_h(a[f], b[c], acc[f + 4][c]);
    __builtin_amdgcn_s_setprio(0);
    GBAR();
  }
  WAIT_VM0();

#pragma unroll
  for (int f = 0; f < 8; ++f) {
    int r0 = brow + wm * 128 + f * 16 + kg * 4;
#pragma unroll
    for (int c = 0; c < 4; ++c) {
      int cc = bcol + wn * 64 + c * 16 + frow;
      float bb = bias[cc];
#pragma unroll
      for (int q = 0; q < 4; ++q)
        C[(size_t)(r0 + q) * H_DIM + cc] = acc[f][c][q] + bb;
    }
  }
}

// ---------------- WKV scan: fp64 state + fp32 __expf (exp rel-err budget ~1e-3) ----------------
// ILP-2, C=64/W=48, tstart clamped >= 0 (clamped chunks start at t=0 with true init).
__global__ void wkv_scan_kernel(const float* __restrict__ kbuf,
                                const unsigned short* __restrict__ vrbuf,
                                const float* __restrict__ tdec,
                                unsigned short* __restrict__ rwh) {
  const int h = (blockIdx.x * 64 + threadIdx.x) * 2;
  const int chunk = blockIdx.y;
  const int b = blockIdx.z;
  const int t0 = chunk * SCAN_C;
  int tstart = t0 - SCAN_W;
  if (tstart < 0) tstart = 0;
  const int tend = t0 + SCAN_C;
  double num0, den0, num1, den1;
  if (tstart == 0) { num0 = num1 = 1.0; den0 = den1 = 1.0; }
  else             { num0 = num1 = 0.0; den0 = den1 = 0.0; }
  const double w0 = (double)tdec[h];
  const double w1 = (double)tdec[h + 1];
  size_t ik = ((size_t)b * T_DIM + tstart) * H_DIM + h;
  size_t iv = ((size_t)b * T_DIM + tstart) * 2048 + h;
  float2 kc = *reinterpret_cast<const float2*>(kbuf + ik);
  unsigned int vc = *reinterpret_cast<const unsigned int*>(vrbuf + iv);
  unsigned int rc = *reinterpret_cast<const unsigned int*>(vrbuf + iv + 1024);
  for (int t = tstart; t < tend; ++t) {
    size_t adv = (t + 1 < tend) ? 1 : 0;
    float2 kn = *reinterpret_cast<const float2*>(kbuf + ik + adv * H_DIM);
    unsigned int vn = *reinterpret_cast<const unsigned int*>(vrbuf + iv + adv * 2048);
    unsigned int rn = *reinterpret_cast<const unsigned int*>(vrbuf + iv + adv * 2048 + 1024);
    if (t >= t0) {
      double p0 = w0 * (double)kc.x, p1 = w1 * (double)kc.y;
      float o0 = (float)fma(p0, den0, num0) / (float)(den0 + p0);
      float o1 = (float)fma(p1, den1, num1) / (float)(den1 + p1);
      float rr0 = 1.0f / (1.0f + __expf(-h2f((unsigned short)(rc & 0xffffu))));
      float rr1 = 1.0f / (1.0f + __expf(-h2f((unsigned short)(rc >> 16))));
      unsigned int wout = (unsigned int)f2h(rr0 * o0) | ((unsigned int)f2h(rr1 * o1) << 16);
      *reinterpret_cast<unsigned int*>(rwh + ik) = wout;
    }
    // fp32 exp (rel err ~2e-7 << 1e-3 budget); accumulation stays fp64 (cancellation-critical)
    float ek0f = __expf(kc.x);
    float ek1f = __expf(kc.y);
    num0 = fma(w0, num0, (double)(ek0f * h2f((unsigned short)(vc & 0xffffu))));
    den0 = fma(w0, den0, (double)ek0f);
    num1 = fma(w1, num1, (double)(ek1f * h2f((unsigned short)(vc >> 16))));
    den1 = fma(w1, den1, (double)ek1f);
    kc = kn; vc = vn; rc = rn;
    ik += H_DIM; iv += 2048;
  }
}

// -------------------------------- host --------------------------------
extern "C" void kernel_launch(void* const* d_in, const int* in_sizes, int n_in,
                              void* d_out, int out_size, void* d_ws, size_t ws_size,
                              hipStream_t stream) {
  const float* x    = (const float*)d_in[0];
  const float* tdec = (const float*)d_in[1];
  const float* tmk  = (const float*)d_in[2];
  const float* tmv  = (const float*)d_in[3];
  const float* tmr  = (const float*)d_in[4];
  const float* Wrec = (const float*)d_in[5];
  const float* Wkey = (const float*)d_in[6];
  const float* Wval = (const float*)d_in[7];
  const float* Wout = (const float*)d_in[8];
  const float* bout = (const float*)d_in[9];
  float* out = (float*)d_out;
  unsigned char* ws = (unsigned char*)d_ws;

  const size_t W2 = (size_t)H_DIM * H_DIM * 2;       // 2MB per fp16 weight
  const size_t BF_FULL = (size_t)M_DIM * H_DIM * 2;  // 32MB fp16 [M,H]
  const size_t NEED = 2 * BF_FULL + 2 * BF_FULL + 5 * W2;  // 138MB
  if (ws_size < NEED) return;

  size_t off = 0;
  unsigned short* XS1H = (unsigned short*)(ws + off); off += BF_FULL;
  unsigned short* XS2H = (unsigned short*)(ws + off); off += BF_FULL;
  unsigned short* VR   = (unsigned short*)(ws + off); off += 2 * BF_FULL;  // [M,2048] fp16
  unsigned short* WK1H = (unsigned short*)(ws + off); off += W2;
  unsigned short* WK2H = (unsigned short*)(ws + off); off += W2;
  unsigned short* WVRH = (unsigned short*)(ws + off); off += 2 * W2;       // [2048,1024] fp16
  unsigned short* WOH  = (unsigned short*)(ws + off); off += W2;

  // fused prep: xs split + weight prep in one dispatch
  prep_kernel<<<dim3(16384 + 4096), dim3(256), 0, stream>>>(
      x, Wrec, Wkey, Wval, Wout, tmk, tmv, tmr, XS1H, XS2H, WK1H, WK2H, WVRH, WOH);

  // fused front: k (fp32 -> d_out) + v|r (fp16 -> VR) in one 1024-block dispatch
  front_kernel<<<dim3(1024), dim3(512), 0, stream>>>(
      XS1H, XS2H, WK1H, WK2H, WVRH, out, VR);

  // WKV scan (ILP-2, C=64, fp32 exp); rw (fp16) reuses XS1H (dead after front)
  unsigned short* RWH = XS1H;
  wkv_scan_kernel<<<dim3(H_DIM / 128, T_DIM / SCAN_C, B_DIM), dim3(64), 0, stream>>>(
      out, VR, tdec, RWH);

  // final projection + bias -> d_out fp32 (R9's 256x256 8-phase)
  gemm_o_kernel<<<dim3(H_DIM / 256, M_DIM / 256), dim3(512), 0, stream>>>(
      RWH, WOH, out, bout);
}